// Round 2
// baseline (366.620 us; speedup 1.0000x reference)
//
#include <hip/hip_runtime.h>
#include <stdint.h>

typedef _Float16 f16;
typedef _Float16 f16x8 __attribute__((ext_vector_type(8)));
typedef float f32x4 __attribute__((ext_vector_type(4)));

#define B_   4
#define S_   2048
#define E_   1024
#define H_   16
#define HD_  64
#define BH_  (B_ * H_)

// ---------------------------------------------------------------- helpers
__device__ __forceinline__ void async_lds16(const void* g, void* l) {
    // global -> LDS direct copy, 16B per lane. LDS dest must be wave-uniform;
    // HW adds lane*16. Generic->AS3 cast via integer truncation (low 32 bits
    // of a generic shared pointer are the LDS offset on gfx9+).
    __builtin_amdgcn_global_load_lds(
        (__attribute__((address_space(1))) void*)(uintptr_t)g,
        (__attribute__((address_space(3))) void*)(uint32_t)(uintptr_t)l,
        16, 0, 0);
}

// ---------------------------------------------------------------- fp32 -> fp16
__global__ __launch_bounds__(256)
void cvt_f32_to_f16(const float* __restrict__ in, f16* __restrict__ out, int n8) {
    int i = blockIdx.x * 256 + threadIdx.x;
    if (i >= n8) return;
    const float4* p = (const float4*)in;
    float4 a = p[2 * i], b = p[2 * i + 1];
    f16x8 o;
    o[0] = (f16)a.x; o[1] = (f16)a.y; o[2] = (f16)a.z; o[3] = (f16)a.w;
    o[4] = (f16)b.x; o[5] = (f16)b.y; o[6] = (f16)b.z; o[7] = (f16)b.w;
    *(f16x8*)(out + 8 * (long)i) = o;
}

// ---------------------------------------------------------------- GEMM  C = A[M,K] * B[N,K]^T
// MODE 0: QKV projection epilogue -> scatter to q[bh][s][d], k[bh][s][d], vT[bh][d][s] (f16)
// MODE 1: out projection epilogue -> fp32 C + bias
template <int MODE>
__global__ __launch_bounds__(256)
void gemm_bt(const f16* __restrict__ A, const f16* __restrict__ Bm,
             const float* __restrict__ bias, float* __restrict__ Cf,
             f16* __restrict__ qo, f16* __restrict__ ko, f16* __restrict__ vto,
             int M, int N, int K)
{
    __shared__ __align__(16) f16 As[128 * 32];
    __shared__ __align__(16) f16 Bs[128 * 32];
    const int tid = threadIdx.x;
    const int wave = tid >> 6, lane = tid & 63;
    const int lo = lane & 15, hi = lane >> 4;
    const int ntn = N >> 7;
    const int tm = blockIdx.x / ntn, tn = blockIdx.x % ntn;
    const long bm0 = (long)tm << 7, bn0 = (long)tn << 7;
    const int wr = (wave >> 1) << 6, wc = (wave & 1) << 6;

    f32x4 acc[4][4] = {};

    for (int k0 = 0; k0 < K; k0 += 32) {
        __syncthreads();  // protect prior iteration's LDS reads
#pragma unroll
        for (int pass = 0; pass < 2; ++pass) {
            const int c = pass * 256 + wave * 64 + lane;    // 16B chunk id, 0..511
            const int row = c >> 2, c4 = c & 3;             // 4 chunks per 32-elem row
            async_lds16(A + (bm0 + row) * K + k0 + c4 * 8,
                        &As[(pass * 256 + wave * 64) * 8]);
            async_lds16(Bm + (bn0 + row) * K + k0 + c4 * 8,
                        &Bs[(pass * 256 + wave * 64) * 8]);
        }
        __syncthreads();  // compiler drains vmcnt before barrier -> LDS valid

        f16x8 af[4], bf[4];
#pragma unroll
        for (int mi = 0; mi < 4; ++mi)
            af[mi] = *(const f16x8*)&As[(wr + mi * 16 + lo) * 32 + hi * 8];
#pragma unroll
        for (int ni = 0; ni < 4; ++ni)
            bf[ni] = *(const f16x8*)&Bs[(wc + ni * 16 + lo) * 32 + hi * 8];
#pragma unroll
        for (int mi = 0; mi < 4; ++mi)
#pragma unroll
            for (int ni = 0; ni < 4; ++ni)
                acc[mi][ni] = __builtin_amdgcn_mfma_f32_16x16x32_f16(
                    af[mi], bf[ni], acc[mi][ni], 0, 0, 0);
    }

    // epilogue: C/D layout col = lane&15, row = 4*(lane>>4)+j
#pragma unroll
    for (int mi = 0; mi < 4; ++mi) {
#pragma unroll
        for (int ni = 0; ni < 4; ++ni) {
#pragma unroll
            for (int j = 0; j < 4; ++j) {
                const long r  = bm0 + wr + mi * 16 + 4 * hi + j;   // global row (B*S)
                const int  cn = (int)bn0 + wc + ni * 16 + lo;      // global col
                const float v = acc[mi][ni][j] + bias[cn];
                if (MODE == 1) {
                    Cf[r * N + cn] = v;
                } else {
                    const int which = cn >> 10, e = cn & 1023;
                    const int h = e >> 6, d = e & 63;
                    const int b = (int)(r >> 11), s = (int)(r & 2047);
                    const long bh = (long)b * H_ + h;
                    const f16 hv = (f16)v;
                    if (which == 0)      qo[(bh * S_ + s) * HD_ + d] = hv;
                    else if (which == 1) ko[(bh * S_ + s) * HD_ + d] = hv;
                    else                 vto[(bh * HD_ + d) * S_ + s] = hv;  // V transposed
                }
            }
        }
    }
}

// ---------------------------------------------------------------- causal flash attention
// grid: x = q-tile (32, reversed for load balance), y = bh (64). 4 waves, 64 q-rows/block.
__global__ __launch_bounds__(256)
void attn_fwd(const f16* __restrict__ qb, const f16* __restrict__ kb,
              const f16* __restrict__ vtb, f16* __restrict__ ob)
{
    __shared__ __align__(16) f16 Ks[64 * 72];       // [kv][d], +8 pad
    __shared__ __align__(16) f16 Vs[64 * 72];       // [d][kv], +8 pad (from V^T)
    __shared__ __align__(16) f16 Ps[4][16 * 72];    // per-wave P, +8 pad
    const int tid = threadIdx.x, wave = tid >> 6, lane = tid & 63;
    const int lo = lane & 15, hi = lane >> 4;
    const int bh = blockIdx.y;
    const int qtile = (int)gridDim.x - 1 - (int)blockIdx.x;  // big tiles first
    const int q0 = qtile * 64;
    const int qw = q0 + wave * 16;          // this wave's first q row
    const long krow0 = (long)bh * S_;

    f16x8 qf[2];
#pragma unroll
    for (int kk = 0; kk < 2; ++kk)
        qf[kk] = *(const f16x8*)&qb[(krow0 + qw + lo) * HD_ + kk * 32 + hi * 8];

    f32x4 o[4] = {};
    float m_r[4], l_r[4];
#pragma unroll
    for (int j = 0; j < 4; ++j) { m_r[j] = -1e30f; l_r[j] = 0.f; }

    const int nt = qtile + 1;
    for (int t = 0; t < nt; ++t) {
        const int kv0 = t * 64;
        __syncthreads();  // prior PV reads done before restaging
#pragma unroll
        for (int pass = 0; pass < 2; ++pass) {
            const int c = pass * 256 + tid;          // 16B chunk, 0..511
            const int row = c >> 3, c8 = c & 7;      // 8 chunks per 64-elem row
            *(uint4*)&Ks[row * 72 + c8 * 8] =
                *(const uint4*)&kb[(krow0 + kv0 + row) * HD_ + c8 * 8];
            *(uint4*)&Vs[row * 72 + c8 * 8] =
                *(const uint4*)&vtb[((long)bh * HD_ + row) * S_ + kv0 + c8 * 8];
        }
        __syncthreads();

        // S = Q K^T : D rows = q (4*hi+j), cols = kv (ni*16+lo)
        f32x4 sc[4] = {};
#pragma unroll
        for (int kk = 0; kk < 2; ++kk) {
#pragma unroll
            for (int ni = 0; ni < 4; ++ni) {
                f16x8 kf = *(const f16x8*)&Ks[(ni * 16 + lo) * 72 + kk * 32 + hi * 8];
                sc[ni] = __builtin_amdgcn_mfma_f32_16x16x32_f16(qf[kk], kf, sc[ni], 0, 0, 0);
            }
        }

        // scale + causal mask
        const bool maskp = (kv0 + 63) > qw;
#pragma unroll
        for (int ni = 0; ni < 4; ++ni)
#pragma unroll
            for (int j = 0; j < 4; ++j) {
                float sv = sc[ni][j] * 0.125f;
                if (maskp && (kv0 + ni * 16 + lo) > (qw + 4 * hi + j)) sv = -1e30f;
                sc[ni][j] = sv;
            }

        // online softmax, wave-parallel (16-lane row groups)
#pragma unroll
        for (int j = 0; j < 4; ++j) {
            float tm = fmaxf(fmaxf(sc[0][j], sc[1][j]), fmaxf(sc[2][j], sc[3][j]));
#pragma unroll
            for (int d = 1; d < 16; d <<= 1) tm = fmaxf(tm, __shfl_xor(tm, d));
            const float mn  = fmaxf(m_r[j], tm);
            const float rsc = __expf(m_r[j] - mn);
            float rs = 0.f;
#pragma unroll
            for (int ni = 0; ni < 4; ++ni) {
                const float p = __expf(sc[ni][j] - mn);
                sc[ni][j] = p;
                rs += p;
            }
#pragma unroll
            for (int d = 1; d < 16; d <<= 1) rs += __shfl_xor(rs, d);
            l_r[j] = l_r[j] * rsc + rs;
            m_r[j] = mn;
#pragma unroll
            for (int ni = 0; ni < 4; ++ni) o[ni][j] *= rsc;
        }

        // P -> LDS (re-fragment for PV A-operand)
#pragma unroll
        for (int ni = 0; ni < 4; ++ni)
#pragma unroll
            for (int j = 0; j < 4; ++j)
                Ps[wave][(4 * hi + j) * 72 + ni * 16 + lo] = (f16)sc[ni][j];
        __syncthreads();

        // O += P V : A = P[q][kv], B = V^T rows = d
#pragma unroll
        for (int kk = 0; kk < 2; ++kk) {
            f16x8 pf = *(const f16x8*)&Ps[wave][lo * 72 + kk * 32 + hi * 8];
#pragma unroll
            for (int ni = 0; ni < 4; ++ni) {
                f16x8 vf = *(const f16x8*)&Vs[(ni * 16 + lo) * 72 + kk * 32 + hi * 8];
                o[ni] = __builtin_amdgcn_mfma_f32_16x16x32_f16(pf, vf, o[ni], 0, 0, 0);
            }
        }
    }

    // normalize + write [b][s][h*64+d] as f16 (input to out-proj GEMM)
    const int b = bh >> 4, h = bh & 15;
#pragma unroll
    for (int ni = 0; ni < 4; ++ni)
#pragma unroll
        for (int j = 0; j < 4; ++j) {
            const int s = qw + 4 * hi + j;
            ob[((long)b * S_ + s) * E_ + h * HD_ + ni * 16 + lo] = (f16)(o[ni][j] / l_r[j]);
        }
}

// ---------------------------------------------------------------- launch
extern "C" void kernel_launch(void* const* d_in, const int* in_sizes, int n_in,
                              void* d_out, int out_size, void* d_ws, size_t ws_size,
                              hipStream_t stream)
{
    (void)in_sizes; (void)n_in; (void)out_size; (void)ws_size;
    const float* x  = (const float*)d_in[0];
    const float* w1 = (const float*)d_in[1];
    const float* b1 = (const float*)d_in[2];
    const float* w2 = (const float*)d_in[3];
    const float* b2 = (const float*)d_in[4];
    float* out = (float*)d_out;

    char* ws = (char*)d_ws;
    f16* xb  = (f16*)ws;  ws += (size_t)8192 * 1024 * 2;
    f16* w1b = (f16*)ws;  ws += (size_t)3072 * 1024 * 2;
    f16* w2b = (f16*)ws;  ws += (size_t)1024 * 1024 * 2;
    f16* qb  = (f16*)ws;  ws += (size_t)BH_ * S_ * HD_ * 2;
    f16* kb  = (f16*)ws;  ws += (size_t)BH_ * S_ * HD_ * 2;
    f16* vtb = (f16*)ws;  ws += (size_t)BH_ * S_ * HD_ * 2;
    f16* ao  = (f16*)ws;  ws += (size_t)8192 * 1024 * 2;   // total ~92.3 MB

    cvt_f32_to_f16<<<dim3(8192 * 1024 / 8 / 256), dim3(256), 0, stream>>>(x,  xb,  8192 * 1024 / 8);
    cvt_f32_to_f16<<<dim3(3072 * 1024 / 8 / 256), dim3(256), 0, stream>>>(w1, w1b, 3072 * 1024 / 8);
    cvt_f32_to_f16<<<dim3(1024 * 1024 / 8 / 256), dim3(256), 0, stream>>>(w2, w2b, 1024 * 1024 / 8);

    gemm_bt<0><<<dim3(64 * 24), dim3(256), 0, stream>>>(
        xb, w1b, b1, nullptr, qb, kb, vtb, 8192, 3072, 1024);

    attn_fwd<<<dim3(32, 64), dim3(256), 0, stream>>>(qb, kb, vtb, ao);

    gemm_bt<1><<<dim3(64 * 8), dim3(256), 0, stream>>>(
        ao, w2b, b2, out, nullptr, nullptr, nullptr, 8192, 1024, 1024);
}